// Round 6
// baseline (122.826 us; speedup 1.0000x reference)
//
#include <hip/hip_runtime.h>

// CRF forward logZ. Inputs: words i32 [2048][256], ThetaB f32 [64][128],
// WA f32 [64][64], E f32 [50002][128]. out: f32 [2048].
// ws: Btb bf16 [50002][64] = 6.4 MB (layout [w][q][kc]);
//     Yws f32 @ +8 MB, Xws f32 @ +12 MB: [128 chains][64 tags][16 sents].
//
// R11: crf fwd/bwd split into SEPARATE 1-WAVE BLOCKS (256 blocks x 64 thr)
//      + tiny join kernel. R9/R10 evidence: 9-deep structural ring still
//      stalls ~535cy/step (700 measured vs 165 busy) -> ring depth is not
//      the limit; the fwd+bwd wave pair shares one CU's TA/L1/MSHR while
//      each pushes 2 divergent 16-line gathers/step, and 128 blocks use
//      only half the chip. 1 wave/CU halves per-CU gather pressure and
//      doubles CU count. Wave body identical to R9 (clean attribution).
//      emis_mfma unchanged from R10.

#define NROWS 50002
#define EOS_T 62
#define BOS_T 63
#define TLEN  256
#define LOG64 4.1588830833596715f
#define YWS_OFF (8u  * 1024u * 1024u)   // bytes into ws
#define XWS_OFF (12u * 1024u * 1024u)

typedef __attribute__((ext_vector_type(4))) short bf16x4;
typedef __attribute__((ext_vector_type(8))) short bf16x8;
typedef __attribute__((ext_vector_type(4))) float f32x4;
typedef __attribute__((ext_vector_type(4))) unsigned int u32x4;

// round-half-up f32->bf16 pair pack (2 add + 1 perm); lo in low 16 bits
static __device__ __forceinline__ unsigned pack_bf2(float lo, float hi) {
    unsigned a = __float_as_uint(lo) + 0x8000u;
    unsigned b = __float_as_uint(hi) + 0x8000u;
    return __builtin_amdgcn_perm(b, a, 0x07060302u);
}
static __device__ __forceinline__ bf16x8 pack8(float4 a, float4 b) {
    union { bf16x8 v; unsigned u[4]; } r;
    r.u[0] = pack_bf2(a.x, a.y); r.u[1] = pack_bf2(a.z, a.w);
    r.u[2] = pack_bf2(b.x, b.y); r.u[3] = pack_bf2(b.z, b.w);
    return r.v;
}
static __device__ __forceinline__ bf16x4 pack4(float f0, float f1, float f2, float f3) {
    union { bf16x4 v; unsigned u[2]; } r;
    r.u[0] = pack_bf2(f0, f1); r.u[1] = pack_bf2(f2, f3);
    return r.v;
}

// one Btb row slice for this lane: 32 contiguous bytes = 2x dwordx4 (crf).
#define GLOAD2(buf, addr)                                                     \
    asm volatile("global_load_dwordx4 %0, %2, off\n\t"                        \
                 "global_load_dwordx4 %1, %2, off offset:16"                  \
                 : "=&v"(buf[0]), "=&v"(buf[1]) : "v"(addr))
#define WLOAD(wd, addr)                                                       \
    asm volatile("global_load_dword %0, %1, off" : "=&v"(wd) : "v"(addr))
#define SWAIT(n)                                                              \
    do { __builtin_amdgcn_sched_barrier(0);                                   \
         asm volatile("s_waitcnt vmcnt(" #n ")");                             \
         __builtin_amdgcn_sched_barrier(0); } while (0)

// one E-row slice for this lane: 4x 32B spans (kc*128 + q-slice), 8x dwordx4.
#define GLOADE(buf, addr)                                                     \
    asm volatile("global_load_dwordx4 %0, %8, off\n\t"                        \
                 "global_load_dwordx4 %1, %8, off offset:16\n\t"              \
                 "global_load_dwordx4 %2, %8, off offset:128\n\t"             \
                 "global_load_dwordx4 %3, %8, off offset:144\n\t"             \
                 "global_load_dwordx4 %4, %8, off offset:256\n\t"             \
                 "global_load_dwordx4 %5, %8, off offset:272\n\t"             \
                 "global_load_dwordx4 %6, %8, off offset:384\n\t"             \
                 "global_load_dwordx4 %7, %8, off offset:400"                 \
                 : "=&v"(buf[0]), "=&v"(buf[1]), "=&v"(buf[2]), "=&v"(buf[3]),\
                   "=&v"(buf[4]), "=&v"(buf[5]), "=&v"(buf[6]), "=&v"(buf[7]) \
                 : "v"(addr))
#define GSTORE2(addr, o0, o1)                                                 \
    asm volatile("global_store_dwordx4 %0, %1, off\n\t"                       \
                 "global_store_dwordx4 %0, %2, off offset:16"                 \
                 :: "v"(addr), "v"(o0), "v"(o1) : "memory")

// ---------------------------------------------------------------------------
// Kernel 1: Btb[w][q*4+kc] = bf16(exp(ThetaB[tag].E[w])); tags 62,63 -> 0.
// (unchanged from R10)
// ---------------------------------------------------------------------------
__global__ __launch_bounds__(64, 1) void emis_mfma(
    const float* __restrict__ ThetaB, const float* __restrict__ E,
    uint2* __restrict__ Btb)
{
    const int l = threadIdx.x & 15;
    const int q = threadIdx.x >> 4;

    bf16x8 Af[4][4];
#pragma unroll
    for (int mt = 0; mt < 4; ++mt)
#pragma unroll
        for (int kc = 0; kc < 4; ++kc) {
            const float4* tp = (const float4*)ThetaB + (mt * 16 + l) * 32 + kc * 8 + q * 2;
            Af[mt][kc] = pack8(tp[0], tp[1]);
        }

    const int base0 = blockIdx.x * 64;
    unsigned long long ea[4], sa[4];
#pragma unroll
    for (int it = 0; it < 4; ++it) {
        int row  = base0 + it * 16 + l;
        int rowc = row < NROWS ? row : NROWS - 1;       // clamped rows write
        ea[it] = (unsigned long long)(const char*)E   + (unsigned long long)rowc * 512u + (unsigned)(q * 32);
        sa[it] = (unsigned long long)(char*)Btb       + (unsigned long long)rowc * 128u + (unsigned)(q * 32);
    }

    asm volatile("s_waitcnt vmcnt(0) lgkmcnt(0)");
    __builtin_amdgcn_sched_barrier(0);

    u32x4 b0[8], b1[8], b2[8];
    GLOADE(b0, ea[0]); GLOADE(b1, ea[1]); GLOADE(b2, ea[2]);   // 24 in flight

    auto ctile = [&](u32x4 (&buf)[8], unsigned long long saddr, int refill,
                     unsigned long long raddr) {
        bf16x8 Bf[4];
#pragma unroll
        for (int kc = 0; kc < 4; ++kc)
            Bf[kc] = pack8(*(const float4*)&buf[kc * 2], *(const float4*)&buf[kc * 2 + 1]);
        if (refill) GLOADE(buf, raddr);
        f32x4 D[4];
#pragma unroll
        for (int mt = 0; mt < 4; ++mt) { f32x4 z = {0.f, 0.f, 0.f, 0.f}; D[mt] = z; }
#pragma unroll
        for (int kc = 0; kc < 4; ++kc)
#pragma unroll
            for (int mt = 0; mt < 4; ++mt)
                D[mt] = __builtin_amdgcn_mfma_f32_16x16x32_bf16(Af[mt][kc], Bf[kc], D[mt], 0, 0, 0);
        u32x4 o0, o1;
#pragma unroll
        for (int mt = 0; mt < 4; ++mt) {
            float v0 = expf(D[mt][0]), v1 = expf(D[mt][1]);
            float v2 = expf(D[mt][2]), v3 = expf(D[mt][3]);
            if (mt == 3 && q == 3) { v2 = 0.f; v3 = 0.f; }     // tags 62, 63
            unsigned px = pack_bf2(v0, v1), py = pack_bf2(v2, v3);
            if (mt < 2) { o0[mt * 2] = px; o0[mt * 2 + 1] = py; }
            else        { o1[(mt - 2) * 2] = px; o1[(mt - 2) * 2 + 1] = py; }
        }
        GSTORE2(saddr, o0, o1);
    };

    SWAIT(16);
    ctile(b0, sa[0], 1, ea[3]);
    SWAIT(18);
    ctile(b1, sa[1], 0, 0);
    SWAIT(12);
    ctile(b2, sa[2], 0, 0);
    SWAIT(6);
    ctile(b0, sa[3], 0, 0);
}

// ---------------------------------------------------------------------------
// Kernel 2: one direction chain per 1-wave block. bid<128: fwd chain bid;
// bid>=128: bwd chain bid-128. Wave body = R9's asm ring, unchanged.
// Epilogue: fwd stores Y = S^T alpha_127; bwd stores X128 f32 products.
// Both at ws[chain*1024 + tag*16 + sent] (f32), Yws/Xws regions.
// ---------------------------------------------------------------------------
__global__ __launch_bounds__(64, 1) void crf_chain(
    const int* __restrict__ words, const float* __restrict__ WA,
    const uint2* __restrict__ Btb, float* __restrict__ Yws,
    float* __restrict__ Xws)
{
    const int lane  = threadIdx.x & 63;
    const int wv    = (int)(blockIdx.x >> 7);    // 0 = fwd, 1 = bwd
    const int chain = (int)(blockIdx.x & 127);
    const int l     = lane & 15;
    const int q     = lane >> 4;
    const int sbase = chain * 16;

    // Transition A-frags. S[i][j] = exp(WA[i][j]) * (j != BOS)/64.
    bf16x4 Sf[4][4];
#pragma unroll
    for (int mt = 0; mt < 4; ++mt)
#pragma unroll
        for (int kc = 0; kc < 4; ++kc) {
            float t[4];
#pragma unroll
            for (int j = 0; j < 4; ++j) {
                const int mg = mt * 16 + l;          // m index
                const int kg = kc * 16 + q * 4 + j;  // k index
                const int ii = wv ? mg : kg;         // WA row
                const int jj = wv ? kg : mg;         // WA col (masked: S's j)
                t[j] = (jj == BOS_T) ? 0.f : expf(WA[ii * 64 + jj]) * 0.015625f;
            }
            Sf[mt][kc] = pack4(t[0], t[1], t[2], t[3]);
        }

    float g[4][4];
#pragma unroll
    for (int kc = 0; kc < 4; ++kc)
#pragma unroll
        for (int e = 0; e < 4; ++e) {
            const int jt = kc * 16 + q * 4 + e;
            g[kc][e] = wv ? expf(WA[jt * 64 + EOS_T]) * 0.015625f
                          : ((jt == BOS_T) ? 0.f : expf(WA[BOS_T * 64 + jt]) * 0.015625f);
        }

    const int wb   = (sbase + l) * TLEN;
    const int tdir = wv ? -1 : 1;
    const int t0   = wv ? 254 : 1;

    const unsigned long long btbp   = (unsigned long long)(const char*)Btb + (unsigned)(q * 32);
    const int*               wordsp = words + wb;

    const int w0 = wordsp[t0];
    const int w1 = wordsp[t0 + 1 * tdir], w2 = wordsp[t0 + 2 * tdir];
    const int w3 = wordsp[t0 + 3 * tdir], w4 = wordsp[t0 + 4 * tdir];
    const int w5 = wordsp[t0 + 5 * tdir], w6 = wordsp[t0 + 6 * tdir];
    const int w7 = wordsp[t0 + 7 * tdir], w8 = wordsp[t0 + 8 * tdir];
    const int w9 = wordsp[t0 + 9 * tdir];

    unsigned long long aI0 = btbp + (unsigned long long)w0 * 128u;
    unsigned long long aA = btbp + (unsigned long long)w1 * 128u;
    unsigned long long aB = btbp + (unsigned long long)w2 * 128u;
    unsigned long long aC = btbp + (unsigned long long)w3 * 128u;
    unsigned long long aD = btbp + (unsigned long long)w4 * 128u;
    unsigned long long aE = btbp + (unsigned long long)w5 * 128u;
    unsigned long long aF = btbp + (unsigned long long)w6 * 128u;
    unsigned long long aG = btbp + (unsigned long long)w7 * 128u;
    unsigned long long aH = btbp + (unsigned long long)w8 * 128u;
    unsigned long long aJ = btbp + (unsigned long long)w9 * 128u;

    asm volatile("s_waitcnt vmcnt(0) lgkmcnt(0)");
    __builtin_amdgcn_sched_barrier(0);

    u32x4 ei[2], ebA[2], ebB[2], ebC[2], ebD[2], ebE[2], ebF[2], ebG[2], ebH[2], ebI[2];
    int wdA, wdB, wdC, wdD, wdE, wdF, wdG, wdH, wdI;
    GLOAD2(ei, aI0);
    GLOAD2(ebA, aA); WLOAD(wdA, (unsigned long long)(wordsp + t0 + 10 * tdir));
    GLOAD2(ebB, aB); WLOAD(wdB, (unsigned long long)(wordsp + t0 + 11 * tdir));
    GLOAD2(ebC, aC); WLOAD(wdC, (unsigned long long)(wordsp + t0 + 12 * tdir));
    GLOAD2(ebD, aD); WLOAD(wdD, (unsigned long long)(wordsp + t0 + 13 * tdir));
    GLOAD2(ebE, aE); WLOAD(wdE, (unsigned long long)(wordsp + t0 + 14 * tdir));
    GLOAD2(ebF, aF); WLOAD(wdF, (unsigned long long)(wordsp + t0 + 15 * tdir));
    GLOAD2(ebG, aG); WLOAD(wdG, (unsigned long long)(wordsp + t0 + 16 * tdir));
    GLOAD2(ebH, aH); WLOAD(wdH, (unsigned long long)(wordsp + t0 + 17 * tdir));
    GLOAD2(ebI, aJ); WLOAD(wdI, (unsigned long long)(wordsp + t0 + 18 * tdir));

    SWAIT(27);                                   // ei (oldest 2) complete

    bf16x4 X[4];
#pragma unroll
    for (int kc = 0; kc < 4; ++kc) {
        unsigned ex = ei[kc >> 1][(kc & 1) * 2];
        unsigned ey = ei[kc >> 1][(kc & 1) * 2 + 1];
        float f0 = __uint_as_float(ex << 16)         * g[kc][0];
        float f1 = __uint_as_float(ex & 0xffff0000u) * g[kc][1];
        float f2 = __uint_as_float(ey << 16)         * g[kc][2];
        float f3 = __uint_as_float(ey & 0xffff0000u) * g[kc][3];
        X[kc] = pack4(f0, f1, f2, f3);
    }

    float xf[4][4];                              // last step's f32 products

    auto substep = [&](u32x4 (&eb)[2], int& wd, int widx) {
        f32x4 D[4];
#pragma unroll
        for (int mt = 0; mt < 4; ++mt) { f32x4 z = {0.f, 0.f, 0.f, 0.f}; D[mt] = z; }
#pragma unroll
        for (int kc = 0; kc < 4; ++kc)
#pragma unroll
            for (int mt = 0; mt < 4; ++mt)
                D[mt] = __builtin_amdgcn_mfma_f32_16x16x16bf16_1k(Sf[mt][kc], X[kc], D[mt], 0, 0, 0);
        SWAIT(24);                               // 9-back group (2G+1W) done
#pragma unroll
        for (int kc = 0; kc < 4; ++kc) {
            unsigned ex = eb[kc >> 1][(kc & 1) * 2];
            unsigned ey = eb[kc >> 1][(kc & 1) * 2 + 1];
            float f0 = __uint_as_float(ex << 16);
            float f1 = __uint_as_float(ex & 0xffff0000u);
            float f2 = __uint_as_float(ey << 16);
            float f3 = __uint_as_float(ey & 0xffff0000u);
            xf[kc][0] = D[kc][0] * f0;  xf[kc][1] = D[kc][1] * f1;
            xf[kc][2] = D[kc][2] * f2;  xf[kc][3] = D[kc][3] * f3;
            X[kc] = pack4(xf[kc][0], xf[kc][1], xf[kc][2], xf[kc][3]);
        }
        unsigned long long a = btbp + (unsigned long long)wd * 128u;
        GLOAD2(eb, a);
        WLOAD(wd, (unsigned long long)(wordsp + widx));
    };

    // 126 steps = 14 x 9; word index bounds: fwd max 1+144=145<256,
    // bwd min 254-144=110>=0.
    for (int i = 0; i < 126; i += 9) {
        substep(ebA, wdA, t0 + tdir * (i + 19));
        substep(ebB, wdB, t0 + tdir * (i + 20));
        substep(ebC, wdC, t0 + tdir * (i + 21));
        substep(ebD, wdD, t0 + tdir * (i + 22));
        substep(ebE, wdE, t0 + tdir * (i + 23));
        substep(ebF, wdF, t0 + tdir * (i + 24));
        substep(ebG, wdG, t0 + tdir * (i + 25));
        substep(ebH, wdH, t0 + tdir * (i + 26));
        substep(ebI, wdI, t0 + tdir * (i + 27));
    }

    if (wv == 0) {
        // extra step: Y = S^T alpha_127 (no emission) -> Yws
        f32x4 D[4];
#pragma unroll
        for (int mt = 0; mt < 4; ++mt) { f32x4 z = {0.f, 0.f, 0.f, 0.f}; D[mt] = z; }
#pragma unroll
        for (int kc = 0; kc < 4; ++kc)
#pragma unroll
            for (int mt = 0; mt < 4; ++mt)
                D[mt] = __builtin_amdgcn_mfma_f32_16x16x16bf16_1k(Sf[mt][kc], X[kc], D[mt], 0, 0, 0);
        float* yp = Yws + chain * 1024 + l;      // [tag*16 + sent]
#pragma unroll
        for (int mt = 0; mt < 4; ++mt)
#pragma unroll
            for (int r = 0; r < 4; ++r)
                yp[(mt * 16 + q * 4 + r) * 16] = D[mt][r];
    } else {
        float* xp = Xws + chain * 1024 + l;
#pragma unroll
        for (int kc = 0; kc < 4; ++kc)
#pragma unroll
            for (int e = 0; e < 4; ++e)
                xp[(kc * 16 + q * 4 + e) * 16] = xf[kc][e];
    }
}

// ---------------------------------------------------------------------------
// Kernel 3: join. out[chain*16+l] = log(sum_tag Y[tag][l]*X[tag][l]) + C.
// One block per chain; lane (l,q) partial-sums tags q*16..q*16+15.
// ---------------------------------------------------------------------------
__global__ __launch_bounds__(64, 1) void crf_join(
    const float* __restrict__ Yws, const float* __restrict__ Xws,
    float* __restrict__ out)
{
    const int chain = (int)blockIdx.x;
    const int lane  = threadIdx.x & 63;
    const int l     = lane & 15;
    const int q     = lane >> 4;
    const float* y = Yws + chain * 1024 + l;
    const float* x = Xws + chain * 1024 + l;
    float p = 0.f;
#pragma unroll
    for (int t = 0; t < 16; ++t)
        p = fmaf(y[(q * 16 + t) * 16], x[(q * 16 + t) * 16], p);
    p += __shfl_xor(p, 16, 64);
    p += __shfl_xor(p, 32, 64);
    if (lane < 16)
        out[chain * 16 + l] = logf(p) + 255.0f * LOG64;
}

extern "C" void kernel_launch(void* const* d_in, const int* in_sizes, int n_in,
                              void* d_out, int out_size, void* d_ws, size_t ws_size,
                              hipStream_t stream) {
    const int*   words  = (const int*)d_in[0];
    const float* ThetaB = (const float*)d_in[1];
    const float* WA     = (const float*)d_in[2];
    const float* E      = (const float*)d_in[3];
    float*       outp   = (float*)d_out;
    uint2*       Btb    = (uint2*)d_ws;                       // 6.4 MB
    float*       Yws    = (float*)((char*)d_ws + YWS_OFF);    // 512 KB
    float*       Xws    = (float*)((char*)d_ws + XWS_OFF);    // 512 KB

    // 782 blocks x 1 wave x 4 word-tiles = 50048 >= 50002 rows
    emis_mfma<<<dim3(782), dim3(64), 0, stream>>>(ThetaB, E, Btb);
    // 256 blocks x 1 wave: bid<128 fwd chains, bid>=128 bwd chains
    crf_chain<<<dim3(256), dim3(64), 0, stream>>>(words, WA, Btb, Yws, Xws);
    // join: one block per chain
    crf_join<<<dim3(128), dim3(64), 0, stream>>>(Yws, Xws, outp);
}

// Round 7
// 118.728 us; speedup vs baseline: 1.0345x; 1.0345x over previous
//
#include <hip/hip_runtime.h>

// CRF forward logZ. Inputs: words i32 [2048][256], ThetaB f32 [64][128],
// WA f32 [64][64], E f32 [50002][128]. out: f32 [2048].
// ws: Btb bf16 [50002][64] = 6.4 MB (layout [w][q][kc]).
//
// R12: (1) REVERT R11's fwd/bwd block split (regressed 4.8us: join launch +
//      Y/X roundtrip, no chain gain -> CU-contention theory dead). Back to
//      R9's fused 128x128 kernel with LDS join.
//      (2) Ring depth 9 -> 14 (126 = 9 iters x 14 substeps). Surviving
//      model: T_step = max(T_compute, L_eff/depth); measured T=700cy at
//      depth 9 => L_eff ~ 6300cy (divergent 16-line gathers retire slowly
//      through TA/L1, not raw latency). Depth 14 is the direct divisor:
//      predict T -> ~450-500cy. 42 outstanding VMEM < 63 limit; steady
//      wait = vmcnt(39); ~210 VGPR at waves_per_eu=1.
//      emis_mfma unchanged from R10.

#define NROWS 50002
#define EOS_T 62
#define BOS_T 63
#define TLEN  256
#define LOG64 4.1588830833596715f

typedef __attribute__((ext_vector_type(4))) short bf16x4;
typedef __attribute__((ext_vector_type(8))) short bf16x8;
typedef __attribute__((ext_vector_type(4))) float f32x4;
typedef __attribute__((ext_vector_type(4))) unsigned int u32x4;

// round-half-up f32->bf16 pair pack (2 add + 1 perm); lo in low 16 bits
static __device__ __forceinline__ unsigned pack_bf2(float lo, float hi) {
    unsigned a = __float_as_uint(lo) + 0x8000u;
    unsigned b = __float_as_uint(hi) + 0x8000u;
    return __builtin_amdgcn_perm(b, a, 0x07060302u);
}
static __device__ __forceinline__ bf16x8 pack8(float4 a, float4 b) {
    union { bf16x8 v; unsigned u[4]; } r;
    r.u[0] = pack_bf2(a.x, a.y); r.u[1] = pack_bf2(a.z, a.w);
    r.u[2] = pack_bf2(b.x, b.y); r.u[3] = pack_bf2(b.z, b.w);
    return r.v;
}
static __device__ __forceinline__ bf16x4 pack4(float f0, float f1, float f2, float f3) {
    union { bf16x4 v; unsigned u[2]; } r;
    r.u[0] = pack_bf2(f0, f1); r.u[1] = pack_bf2(f2, f3);
    return r.v;
}

// one Btb row slice for this lane: 32 contiguous bytes = 2x dwordx4 (crf).
#define GLOAD2(buf, addr)                                                     \
    asm volatile("global_load_dwordx4 %0, %2, off\n\t"                        \
                 "global_load_dwordx4 %1, %2, off offset:16"                  \
                 : "=&v"(buf[0]), "=&v"(buf[1]) : "v"(addr))
#define WLOAD(wd, addr)                                                       \
    asm volatile("global_load_dword %0, %1, off" : "=&v"(wd) : "v"(addr))
#define SWAIT(n)                                                              \
    do { __builtin_amdgcn_sched_barrier(0);                                   \
         asm volatile("s_waitcnt vmcnt(" #n ")");                             \
         __builtin_amdgcn_sched_barrier(0); } while (0)

// one E-row slice for this lane: 4x 32B spans (kc*128 + q-slice), 8x dwordx4.
#define GLOADE(buf, addr)                                                     \
    asm volatile("global_load_dwordx4 %0, %8, off\n\t"                        \
                 "global_load_dwordx4 %1, %8, off offset:16\n\t"              \
                 "global_load_dwordx4 %2, %8, off offset:128\n\t"             \
                 "global_load_dwordx4 %3, %8, off offset:144\n\t"             \
                 "global_load_dwordx4 %4, %8, off offset:256\n\t"             \
                 "global_load_dwordx4 %5, %8, off offset:272\n\t"             \
                 "global_load_dwordx4 %6, %8, off offset:384\n\t"             \
                 "global_load_dwordx4 %7, %8, off offset:400"                 \
                 : "=&v"(buf[0]), "=&v"(buf[1]), "=&v"(buf[2]), "=&v"(buf[3]),\
                   "=&v"(buf[4]), "=&v"(buf[5]), "=&v"(buf[6]), "=&v"(buf[7]) \
                 : "v"(addr))
#define GSTORE2(addr, o0, o1)                                                 \
    asm volatile("global_store_dwordx4 %0, %1, off\n\t"                       \
                 "global_store_dwordx4 %0, %2, off offset:16"                 \
                 :: "v"(addr), "v"(o0), "v"(o1) : "memory")

// ---------------------------------------------------------------------------
// Kernel 1: Btb[w][q*4+kc] = bf16(exp(ThetaB[tag].E[w])); tags 62,63 -> 0.
// (unchanged from R10)
// ---------------------------------------------------------------------------
__global__ __launch_bounds__(64, 1) void emis_mfma(
    const float* __restrict__ ThetaB, const float* __restrict__ E,
    uint2* __restrict__ Btb)
{
    const int l = threadIdx.x & 15;
    const int q = threadIdx.x >> 4;

    bf16x8 Af[4][4];
#pragma unroll
    for (int mt = 0; mt < 4; ++mt)
#pragma unroll
        for (int kc = 0; kc < 4; ++kc) {
            const float4* tp = (const float4*)ThetaB + (mt * 16 + l) * 32 + kc * 8 + q * 2;
            Af[mt][kc] = pack8(tp[0], tp[1]);
        }

    const int base0 = blockIdx.x * 64;
    unsigned long long ea[4], sa[4];
#pragma unroll
    for (int it = 0; it < 4; ++it) {
        int row  = base0 + it * 16 + l;
        int rowc = row < NROWS ? row : NROWS - 1;       // clamped rows write
        ea[it] = (unsigned long long)(const char*)E   + (unsigned long long)rowc * 512u + (unsigned)(q * 32);
        sa[it] = (unsigned long long)(char*)Btb       + (unsigned long long)rowc * 128u + (unsigned)(q * 32);
    }

    asm volatile("s_waitcnt vmcnt(0) lgkmcnt(0)");
    __builtin_amdgcn_sched_barrier(0);

    u32x4 b0[8], b1[8], b2[8];
    GLOADE(b0, ea[0]); GLOADE(b1, ea[1]); GLOADE(b2, ea[2]);   // 24 in flight

    auto ctile = [&](u32x4 (&buf)[8], unsigned long long saddr, int refill,
                     unsigned long long raddr) {
        bf16x8 Bf[4];
#pragma unroll
        for (int kc = 0; kc < 4; ++kc)
            Bf[kc] = pack8(*(const float4*)&buf[kc * 2], *(const float4*)&buf[kc * 2 + 1]);
        if (refill) GLOADE(buf, raddr);
        f32x4 D[4];
#pragma unroll
        for (int mt = 0; mt < 4; ++mt) { f32x4 z = {0.f, 0.f, 0.f, 0.f}; D[mt] = z; }
#pragma unroll
        for (int kc = 0; kc < 4; ++kc)
#pragma unroll
            for (int mt = 0; mt < 4; ++mt)
                D[mt] = __builtin_amdgcn_mfma_f32_16x16x32_bf16(Af[mt][kc], Bf[kc], D[mt], 0, 0, 0);
        u32x4 o0, o1;
#pragma unroll
        for (int mt = 0; mt < 4; ++mt) {
            float v0 = expf(D[mt][0]), v1 = expf(D[mt][1]);
            float v2 = expf(D[mt][2]), v3 = expf(D[mt][3]);
            if (mt == 3 && q == 3) { v2 = 0.f; v3 = 0.f; }     // tags 62, 63
            unsigned px = pack_bf2(v0, v1), py = pack_bf2(v2, v3);
            if (mt < 2) { o0[mt * 2] = px; o0[mt * 2 + 1] = py; }
            else        { o1[(mt - 2) * 2] = px; o1[(mt - 2) * 2 + 1] = py; }
        }
        GSTORE2(saddr, o0, o1);
    };

    SWAIT(16);
    ctile(b0, sa[0], 1, ea[3]);
    SWAIT(18);
    ctile(b1, sa[1], 0, 0);
    SWAIT(12);
    ctile(b2, sa[2], 0, 0);
    SWAIT(6);
    ctile(b0, sa[3], 0, 0);
}

// ---------------------------------------------------------------------------
// Kernel 2: fwd/bwd recurrence, fully in registers. Fused (R9 epilogue),
// ring depth 14 (126 = 9 x 14). Substep s drains group issued at s-14 via
// constant vmcnt(39); issues 3 VMEM (2 gather dwordx4 + 1 word).
// fwd (wv=0): A = S^T, X' = (S^T X) o e_t; bwd (wv=1): X' = e_t o (S X).
// Join: z = (S^T alpha_127) . (e_128 o q_129) via one LDS tile + dot.
// ---------------------------------------------------------------------------
__global__ __launch_bounds__(128, 1) void crf_fwdbwd(
    const int* __restrict__ words, const float* __restrict__ WA,
    const uint2* __restrict__ Btb, float* __restrict__ out)
{
    __shared__ float ytile[16 * 68];
    const int lane  = threadIdx.x & 63;
    const int wv    = threadIdx.x >> 6;          // 0 = fwd, 1 = bwd
    const int l     = lane & 15;
    const int q     = lane >> 4;
    const int sbase = blockIdx.x * 16;

    // Transition A-frags. S[i][j] = exp(WA[i][j]) * (j != BOS)/64.
    bf16x4 Sf[4][4];
#pragma unroll
    for (int mt = 0; mt < 4; ++mt)
#pragma unroll
        for (int kc = 0; kc < 4; ++kc) {
            float t[4];
#pragma unroll
            for (int j = 0; j < 4; ++j) {
                const int mg = mt * 16 + l;          // m index
                const int kg = kc * 16 + q * 4 + j;  // k index
                const int ii = wv ? mg : kg;         // WA row
                const int jj = wv ? kg : mg;         // WA col (masked: S's j)
                t[j] = (jj == BOS_T) ? 0.f : expf(WA[ii * 64 + jj]) * 0.015625f;
            }
            Sf[mt][kc] = pack4(t[0], t[1], t[2], t[3]);
        }

    float g[4][4];
#pragma unroll
    for (int kc = 0; kc < 4; ++kc)
#pragma unroll
        for (int e = 0; e < 4; ++e) {
            const int jt = kc * 16 + q * 4 + e;
            g[kc][e] = wv ? expf(WA[jt * 64 + EOS_T]) * 0.015625f
                          : ((jt == BOS_T) ? 0.f : expf(WA[BOS_T * 64 + jt]) * 0.015625f);
        }

    const int wb   = (sbase + l) * TLEN;
    const int tdir = wv ? -1 : 1;
    const int t0   = wv ? 254 : 1;

    const unsigned long long btbp   = (unsigned long long)(const char*)Btb + (unsigned)(q * 32);
    const int*               wordsp = words + wb;

    // -------- prologue: 15 words via normal loads, then asm-issue region ----
    const int w0  = wordsp[t0];
    const int w1  = wordsp[t0 + 1  * tdir], w2  = wordsp[t0 + 2  * tdir];
    const int w3  = wordsp[t0 + 3  * tdir], w4  = wordsp[t0 + 4  * tdir];
    const int w5  = wordsp[t0 + 5  * tdir], w6  = wordsp[t0 + 6  * tdir];
    const int w7  = wordsp[t0 + 7  * tdir], w8  = wordsp[t0 + 8  * tdir];
    const int w9  = wordsp[t0 + 9  * tdir], w10 = wordsp[t0 + 10 * tdir];
    const int w11 = wordsp[t0 + 11 * tdir], w12 = wordsp[t0 + 12 * tdir];
    const int w13 = wordsp[t0 + 13 * tdir], w14 = wordsp[t0 + 14 * tdir];

    unsigned long long aI = btbp + (unsigned long long)w0  * 128u;
    unsigned long long a0 = btbp + (unsigned long long)w1  * 128u;
    unsigned long long a1 = btbp + (unsigned long long)w2  * 128u;
    unsigned long long a2 = btbp + (unsigned long long)w3  * 128u;
    unsigned long long a3 = btbp + (unsigned long long)w4  * 128u;
    unsigned long long a4 = btbp + (unsigned long long)w5  * 128u;
    unsigned long long a5 = btbp + (unsigned long long)w6  * 128u;
    unsigned long long a6 = btbp + (unsigned long long)w7  * 128u;
    unsigned long long a7 = btbp + (unsigned long long)w8  * 128u;
    unsigned long long a8 = btbp + (unsigned long long)w9  * 128u;
    unsigned long long a9 = btbp + (unsigned long long)w10 * 128u;
    unsigned long long aA = btbp + (unsigned long long)w11 * 128u;
    unsigned long long aB = btbp + (unsigned long long)w12 * 128u;
    unsigned long long aC = btbp + (unsigned long long)w13 * 128u;
    unsigned long long aD = btbp + (unsigned long long)w14 * 128u;

    // drain ALL compiler-issued vmem so manual vmcnt counts are exact
    asm volatile("s_waitcnt vmcnt(0) lgkmcnt(0)");
    __builtin_amdgcn_sched_barrier(0);

    u32x4 ei[2], e0[2], e1[2], e2[2], e3[2], e4[2], e5[2], e6[2],
          e7[2], e8[2], e9[2], eA[2], eB[2], eC[2], eD[2];
    int d0, d1, d2, d3, d4, d5, d6, d7, d8, d9, dA, dB, dC, dD;
    // issue groups: [ei:2], then 14x [2 gathers + 1 word] = 44 ops
    GLOAD2(ei, aI);
    GLOAD2(e0, a0); WLOAD(d0, (unsigned long long)(wordsp + t0 + 15 * tdir));
    GLOAD2(e1, a1); WLOAD(d1, (unsigned long long)(wordsp + t0 + 16 * tdir));
    GLOAD2(e2, a2); WLOAD(d2, (unsigned long long)(wordsp + t0 + 17 * tdir));
    GLOAD2(e3, a3); WLOAD(d3, (unsigned long long)(wordsp + t0 + 18 * tdir));
    GLOAD2(e4, a4); WLOAD(d4, (unsigned long long)(wordsp + t0 + 19 * tdir));
    GLOAD2(e5, a5); WLOAD(d5, (unsigned long long)(wordsp + t0 + 20 * tdir));
    GLOAD2(e6, a6); WLOAD(d6, (unsigned long long)(wordsp + t0 + 21 * tdir));
    GLOAD2(e7, a7); WLOAD(d7, (unsigned long long)(wordsp + t0 + 22 * tdir));
    GLOAD2(e8, a8); WLOAD(d8, (unsigned long long)(wordsp + t0 + 23 * tdir));
    GLOAD2(e9, a9); WLOAD(d9, (unsigned long long)(wordsp + t0 + 24 * tdir));
    GLOAD2(eA, aA); WLOAD(dA, (unsigned long long)(wordsp + t0 + 25 * tdir));
    GLOAD2(eB, aB); WLOAD(dB, (unsigned long long)(wordsp + t0 + 26 * tdir));
    GLOAD2(eC, aC); WLOAD(dC, (unsigned long long)(wordsp + t0 + 27 * tdir));
    GLOAD2(eD, aD); WLOAD(dD, (unsigned long long)(wordsp + t0 + 28 * tdir));

    SWAIT(42);                                   // ei (oldest 2) complete

    // X init = g o e_{t0}   (entry kc at ei[kc>>1], words (kc&1)*2, +1)
    bf16x4 X[4];
#pragma unroll
    for (int kc = 0; kc < 4; ++kc) {
        unsigned ex = ei[kc >> 1][(kc & 1) * 2];
        unsigned ey = ei[kc >> 1][(kc & 1) * 2 + 1];
        float f0 = __uint_as_float(ex << 16)         * g[kc][0];
        float f1 = __uint_as_float(ex & 0xffff0000u) * g[kc][1];
        float f2 = __uint_as_float(ey << 16)         * g[kc][2];
        float f3 = __uint_as_float(ey & 0xffff0000u) * g[kc][3];
        X[kc] = pack4(f0, f1, f2, f3);
    }

    float xf[4][4];                              // last step's f32 products

    // substep for step s: MFMA (regs only) BEFORE the wait; drain group
    // issued at s-14 (vmcnt 39), consume its emission, refill for s+14,
    // fetch word for s+28. Exactly 3 asm VMEM issued per substep.
    auto substep = [&](u32x4 (&eb)[2], int& wd, int widx) {
        f32x4 D[4];
#pragma unroll
        for (int mt = 0; mt < 4; ++mt) { f32x4 z = {0.f, 0.f, 0.f, 0.f}; D[mt] = z; }
#pragma unroll
        for (int kc = 0; kc < 4; ++kc)
#pragma unroll
            for (int mt = 0; mt < 4; ++mt)
                D[mt] = __builtin_amdgcn_mfma_f32_16x16x16bf16_1k(Sf[mt][kc], X[kc], D[mt], 0, 0, 0);
        SWAIT(39);                               // 14-back group (2G+1W) done
#pragma unroll
        for (int kc = 0; kc < 4; ++kc) {
            unsigned ex = eb[kc >> 1][(kc & 1) * 2];
            unsigned ey = eb[kc >> 1][(kc & 1) * 2 + 1];
            float f0 = __uint_as_float(ex << 16);
            float f1 = __uint_as_float(ex & 0xffff0000u);
            float f2 = __uint_as_float(ey << 16);
            float f3 = __uint_as_float(ey & 0xffff0000u);
            xf[kc][0] = D[kc][0] * f0;  xf[kc][1] = D[kc][1] * f1;
            xf[kc][2] = D[kc][2] * f2;  xf[kc][3] = D[kc][3] * f3;
            X[kc] = pack4(xf[kc][0], xf[kc][1], xf[kc][2], xf[kc][3]);
        }
        unsigned long long a = btbp + (unsigned long long)wd * 128u;
        GLOAD2(eb, a);
        WLOAD(wd, (unsigned long long)(wordsp + widx));
    };

    // 126 steps = 9 x 14; word index bounds: fwd max 1+(112+13+29)=155<256,
    // bwd min 254-154=100>=0.
    for (int i = 0; i < 126; i += 14) {
        substep(e0, d0, t0 + tdir * (i + 29));
        substep(e1, d1, t0 + tdir * (i + 30));
        substep(e2, d2, t0 + tdir * (i + 31));
        substep(e3, d3, t0 + tdir * (i + 32));
        substep(e4, d4, t0 + tdir * (i + 33));
        substep(e5, d5, t0 + tdir * (i + 34));
        substep(e6, d6, t0 + tdir * (i + 35));
        substep(e7, d7, t0 + tdir * (i + 36));
        substep(e8, d8, t0 + tdir * (i + 37));
        substep(e9, d9, t0 + tdir * (i + 38));
        substep(eA, dA, t0 + tdir * (i + 39));
        substep(eB, dB, t0 + tdir * (i + 40));
        substep(eC, dC, t0 + tdir * (i + 41));
        substep(eD, dD, t0 + tdir * (i + 42));
    }

    if (wv == 0) {
        // extra step: Y = S^T alpha_127 (no emission) -> LDS
        f32x4 D[4];
#pragma unroll
        for (int mt = 0; mt < 4; ++mt) { f32x4 z = {0.f, 0.f, 0.f, 0.f}; D[mt] = z; }
#pragma unroll
        for (int kc = 0; kc < 4; ++kc)
#pragma unroll
            for (int mt = 0; mt < 4; ++mt)
                D[mt] = __builtin_amdgcn_mfma_f32_16x16x16bf16_1k(Sf[mt][kc], X[kc], D[mt], 0, 0, 0);
#pragma unroll
        for (int mt = 0; mt < 4; ++mt) {
            float4 o = {D[mt][0], D[mt][1], D[mt][2], D[mt][3]};
            *(float4*)&ytile[l * 68 + mt * 16 + q * 4] = o;
        }
    }
    __syncthreads();
    if (wv == 1) {
        // z[s] = sum_tag Y[tag][s] * X128[tag][s]
        float p = 0.f;
#pragma unroll
        for (int mt = 0; mt < 4; ++mt)
#pragma unroll
            for (int r = 0; r < 4; ++r)
                p = fmaf(ytile[l * 68 + mt * 16 + q * 4 + r], xf[mt][r], p);
        p += __shfl_xor(p, 16, 64);
        p += __shfl_xor(p, 32, 64);
        if (lane < 16)
            out[sbase + l] = logf(p) + 255.0f * LOG64;
    }
}

extern "C" void kernel_launch(void* const* d_in, const int* in_sizes, int n_in,
                              void* d_out, int out_size, void* d_ws, size_t ws_size,
                              hipStream_t stream) {
    const int*   words  = (const int*)d_in[0];
    const float* ThetaB = (const float*)d_in[1];
    const float* WA     = (const float*)d_in[2];
    const float* E      = (const float*)d_in[3];
    float*       outp   = (float*)d_out;
    uint2*       Btb    = (uint2*)d_ws;          // 50002*128 B = 6.4 MB

    // 782 blocks x 1 wave x 4 word-tiles = 50048 >= 50002 rows
    emis_mfma<<<dim3(782), dim3(64), 0, stream>>>(ThetaB, E, Btb);
    // 128 blocks x (fwd wave + bwd wave), 16 sentences each
    crf_fwdbwd<<<dim3(128), dim3(128), 0, stream>>>(words, WA, Btb, outp);
}

// Round 9
// 117.589 us; speedup vs baseline: 1.0445x; 1.0097x over previous
//
#include <hip/hip_runtime.h>

// CRF forward logZ. Inputs: words i32 [2048][256], ThetaB f32 [64][128],
// WA f32 [64][64], E f32 [50002][128]. out: f32 [2048].
// ws: Btb bf16 [50002][64] = 6.4 MB (layout [w][q][kc]).
//
// R14: revert R13 (NaN: asm ds_read assumed wlds at LDS offset 0 - invalid).
//      Base = proven R12 (118.7us). ONE change: batched vmcnt waits.
//      m135: s_waitcnt vmcnt(N) costs 156-332cy even L2-warm (fixed
//      scoreboard-drain cost per WAIT instruction). R12 = 1 wait/substep
//      -> ~200-300 of the ~700cy/step may be wait overhead. Now: 1 wait
//      per 7 substeps, vmcnt(21) drains 7 groups (3 ops each) at once;
//      7 consume/refill substeps follow with no wait. Loads, buffers,
//      dependencies identical to R12 - only wait placement changed.

#define NROWS 50002
#define EOS_T 62
#define BOS_T 63
#define TLEN  256
#define LOG64 4.1588830833596715f

typedef __attribute__((ext_vector_type(4))) short bf16x4;
typedef __attribute__((ext_vector_type(8))) short bf16x8;
typedef __attribute__((ext_vector_type(4))) float f32x4;
typedef __attribute__((ext_vector_type(4))) unsigned int u32x4;

// round-half-up f32->bf16 pair pack (2 add + 1 perm); lo in low 16 bits
static __device__ __forceinline__ unsigned pack_bf2(float lo, float hi) {
    unsigned a = __float_as_uint(lo) + 0x8000u;
    unsigned b = __float_as_uint(hi) + 0x8000u;
    return __builtin_amdgcn_perm(b, a, 0x07060302u);
}
static __device__ __forceinline__ bf16x8 pack8(float4 a, float4 b) {
    union { bf16x8 v; unsigned u[4]; } r;
    r.u[0] = pack_bf2(a.x, a.y); r.u[1] = pack_bf2(a.z, a.w);
    r.u[2] = pack_bf2(b.x, b.y); r.u[3] = pack_bf2(b.z, b.w);
    return r.v;
}
static __device__ __forceinline__ bf16x4 pack4(float f0, float f1, float f2, float f3) {
    union { bf16x4 v; unsigned u[2]; } r;
    r.u[0] = pack_bf2(f0, f1); r.u[1] = pack_bf2(f2, f3);
    return r.v;
}

// one Btb row slice for this lane: 32 contiguous bytes = 2x dwordx4 (crf).
#define GLOAD2(buf, addr)                                                     \
    asm volatile("global_load_dwordx4 %0, %2, off\n\t"                        \
                 "global_load_dwordx4 %1, %2, off offset:16"                  \
                 : "=&v"(buf[0]), "=&v"(buf[1]) : "v"(addr))
#define WLOAD(wd, addr)                                                       \
    asm volatile("global_load_dword %0, %1, off" : "=&v"(wd) : "v"(addr))
#define SWAIT(n)                                                              \
    do { __builtin_amdgcn_sched_barrier(0);                                   \
         asm volatile("s_waitcnt vmcnt(" #n ")");                             \
         __builtin_amdgcn_sched_barrier(0); } while (0)

// one E-row slice for this lane: 4x 32B spans (kc*128 + q-slice), 8x dwordx4.
#define GLOADE(buf, addr)                                                     \
    asm volatile("global_load_dwordx4 %0, %8, off\n\t"                        \
                 "global_load_dwordx4 %1, %8, off offset:16\n\t"              \
                 "global_load_dwordx4 %2, %8, off offset:128\n\t"             \
                 "global_load_dwordx4 %3, %8, off offset:144\n\t"             \
                 "global_load_dwordx4 %4, %8, off offset:256\n\t"             \
                 "global_load_dwordx4 %5, %8, off offset:272\n\t"             \
                 "global_load_dwordx4 %6, %8, off offset:384\n\t"             \
                 "global_load_dwordx4 %7, %8, off offset:400"                 \
                 : "=&v"(buf[0]), "=&v"(buf[1]), "=&v"(buf[2]), "=&v"(buf[3]),\
                   "=&v"(buf[4]), "=&v"(buf[5]), "=&v"(buf[6]), "=&v"(buf[7]) \
                 : "v"(addr))
#define GSTORE2(addr, o0, o1)                                                 \
    asm volatile("global_store_dwordx4 %0, %1, off\n\t"                       \
                 "global_store_dwordx4 %0, %2, off offset:16"                 \
                 :: "v"(addr), "v"(o0), "v"(o1) : "memory")

// ---------------------------------------------------------------------------
// Kernel 1: Btb[w][q*4+kc] = bf16(exp(ThetaB[tag].E[w])); tags 62,63 -> 0.
// (unchanged from R10)
// ---------------------------------------------------------------------------
__global__ __launch_bounds__(64, 1) void emis_mfma(
    const float* __restrict__ ThetaB, const float* __restrict__ E,
    uint2* __restrict__ Btb)
{
    const int l = threadIdx.x & 15;
    const int q = threadIdx.x >> 4;

    bf16x8 Af[4][4];
#pragma unroll
    for (int mt = 0; mt < 4; ++mt)
#pragma unroll
        for (int kc = 0; kc < 4; ++kc) {
            const float4* tp = (const float4*)ThetaB + (mt * 16 + l) * 32 + kc * 8 + q * 2;
            Af[mt][kc] = pack8(tp[0], tp[1]);
        }

    const int base0 = blockIdx.x * 64;
    unsigned long long ea[4], sa[4];
#pragma unroll
    for (int it = 0; it < 4; ++it) {
        int row  = base0 + it * 16 + l;
        int rowc = row < NROWS ? row : NROWS - 1;       // clamped rows write
        ea[it] = (unsigned long long)(const char*)E   + (unsigned long long)rowc * 512u + (unsigned)(q * 32);
        sa[it] = (unsigned long long)(char*)Btb       + (unsigned long long)rowc * 128u + (unsigned)(q * 32);
    }

    asm volatile("s_waitcnt vmcnt(0) lgkmcnt(0)");
    __builtin_amdgcn_sched_barrier(0);

    u32x4 b0[8], b1[8], b2[8];
    GLOADE(b0, ea[0]); GLOADE(b1, ea[1]); GLOADE(b2, ea[2]);   // 24 in flight

    auto ctile = [&](u32x4 (&buf)[8], unsigned long long saddr, int refill,
                     unsigned long long raddr) {
        bf16x8 Bf[4];
#pragma unroll
        for (int kc = 0; kc < 4; ++kc)
            Bf[kc] = pack8(*(const float4*)&buf[kc * 2], *(const float4*)&buf[kc * 2 + 1]);
        if (refill) GLOADE(buf, raddr);
        f32x4 D[4];
#pragma unroll
        for (int mt = 0; mt < 4; ++mt) { f32x4 z = {0.f, 0.f, 0.f, 0.f}; D[mt] = z; }
#pragma unroll
        for (int kc = 0; kc < 4; ++kc)
#pragma unroll
            for (int mt = 0; mt < 4; ++mt)
                D[mt] = __builtin_amdgcn_mfma_f32_16x16x32_bf16(Af[mt][kc], Bf[kc], D[mt], 0, 0, 0);
        u32x4 o0, o1;
#pragma unroll
        for (int mt = 0; mt < 4; ++mt) {
            float v0 = expf(D[mt][0]), v1 = expf(D[mt][1]);
            float v2 = expf(D[mt][2]), v3 = expf(D[mt][3]);
            if (mt == 3 && q == 3) { v2 = 0.f; v3 = 0.f; }     // tags 62, 63
            unsigned px = pack_bf2(v0, v1), py = pack_bf2(v2, v3);
            if (mt < 2) { o0[mt * 2] = px; o0[mt * 2 + 1] = py; }
            else        { o1[(mt - 2) * 2] = px; o1[(mt - 2) * 2 + 1] = py; }
        }
        GSTORE2(saddr, o0, o1);
    };

    SWAIT(16);
    ctile(b0, sa[0], 1, ea[3]);
    SWAIT(18);
    ctile(b1, sa[1], 0, 0);
    SWAIT(12);
    ctile(b2, sa[2], 0, 0);
    SWAIT(6);
    ctile(b0, sa[3], 0, 0);
}

// ---------------------------------------------------------------------------
// Kernel 2: fwd/bwd recurrence, fully in registers. Ring depth 14; waits
// BATCHED: one vmcnt(21) per 7 substeps drains 7 groups (2 gathers + 1
// word each); the 7 consume/refill substeps run wait-free.
// fwd (wv=0): A = S^T, X' = (S^T X) o e_t; bwd (wv=1): X' = e_t o (S X).
// Join: z = (S^T alpha_127) . (e_128 o q_129) via one LDS tile + dot.
// ---------------------------------------------------------------------------
__global__ __launch_bounds__(128, 1) void crf_fwdbwd(
    const int* __restrict__ words, const float* __restrict__ WA,
    const uint2* __restrict__ Btb, float* __restrict__ out)
{
    __shared__ float ytile[16 * 68];
    const int lane  = threadIdx.x & 63;
    const int wv    = threadIdx.x >> 6;          // 0 = fwd, 1 = bwd
    const int l     = lane & 15;
    const int q     = lane >> 4;
    const int sbase = blockIdx.x * 16;

    // Transition A-frags. S[i][j] = exp(WA[i][j]) * (j != BOS)/64.
    bf16x4 Sf[4][4];
#pragma unroll
    for (int mt = 0; mt < 4; ++mt)
#pragma unroll
        for (int kc = 0; kc < 4; ++kc) {
            float t[4];
#pragma unroll
            for (int j = 0; j < 4; ++j) {
                const int mg = mt * 16 + l;          // m index
                const int kg = kc * 16 + q * 4 + j;  // k index
                const int ii = wv ? mg : kg;         // WA row
                const int jj = wv ? kg : mg;         // WA col (masked: S's j)
                t[j] = (jj == BOS_T) ? 0.f : expf(WA[ii * 64 + jj]) * 0.015625f;
            }
            Sf[mt][kc] = pack4(t[0], t[1], t[2], t[3]);
        }

    float g[4][4];
#pragma unroll
    for (int kc = 0; kc < 4; ++kc)
#pragma unroll
        for (int e = 0; e < 4; ++e) {
            const int jt = kc * 16 + q * 4 + e;
            g[kc][e] = wv ? expf(WA[jt * 64 + EOS_T]) * 0.015625f
                          : ((jt == BOS_T) ? 0.f : expf(WA[BOS_T * 64 + jt]) * 0.015625f);
        }

    const int wb   = (sbase + l) * TLEN;
    const int tdir = wv ? -1 : 1;
    const int t0   = wv ? 254 : 1;

    const unsigned long long btbp   = (unsigned long long)(const char*)Btb + (unsigned)(q * 32);
    const int*               wordsp = words + wb;

    // -------- prologue: 15 words via normal loads, then asm-issue region ----
    const int w0  = wordsp[t0];
    const int w1  = wordsp[t0 + 1  * tdir], w2  = wordsp[t0 + 2  * tdir];
    const int w3  = wordsp[t0 + 3  * tdir], w4  = wordsp[t0 + 4  * tdir];
    const int w5  = wordsp[t0 + 5  * tdir], w6  = wordsp[t0 + 6  * tdir];
    const int w7  = wordsp[t0 + 7  * tdir], w8  = wordsp[t0 + 8  * tdir];
    const int w9  = wordsp[t0 + 9  * tdir], w10 = wordsp[t0 + 10 * tdir];
    const int w11 = wordsp[t0 + 11 * tdir], w12 = wordsp[t0 + 12 * tdir];
    const int w13 = wordsp[t0 + 13 * tdir], w14 = wordsp[t0 + 14 * tdir];

    unsigned long long aI = btbp + (unsigned long long)w0  * 128u;
    unsigned long long a0 = btbp + (unsigned long long)w1  * 128u;
    unsigned long long a1 = btbp + (unsigned long long)w2  * 128u;
    unsigned long long a2 = btbp + (unsigned long long)w3  * 128u;
    unsigned long long a3 = btbp + (unsigned long long)w4  * 128u;
    unsigned long long a4 = btbp + (unsigned long long)w5  * 128u;
    unsigned long long a5 = btbp + (unsigned long long)w6  * 128u;
    unsigned long long a6 = btbp + (unsigned long long)w7  * 128u;
    unsigned long long a7 = btbp + (unsigned long long)w8  * 128u;
    unsigned long long a8 = btbp + (unsigned long long)w9  * 128u;
    unsigned long long a9 = btbp + (unsigned long long)w10 * 128u;
    unsigned long long aA = btbp + (unsigned long long)w11 * 128u;
    unsigned long long aB = btbp + (unsigned long long)w12 * 128u;
    unsigned long long aC = btbp + (unsigned long long)w13 * 128u;
    unsigned long long aD = btbp + (unsigned long long)w14 * 128u;

    // drain ALL compiler-issued vmem so manual vmcnt counts are exact
    asm volatile("s_waitcnt vmcnt(0) lgkmcnt(0)");
    __builtin_amdgcn_sched_barrier(0);

    u32x4 ei[2], e0[2], e1[2], e2[2], e3[2], e4[2], e5[2], e6[2],
          e7[2], e8[2], e9[2], eA[2], eB[2], eC[2], eD[2];
    int d0, d1, d2, d3, d4, d5, d6, d7, d8, d9, dA, dB, dC, dD;
    // issue groups: [ei:2], then 14x [2 gathers + 1 word] = 44 ops
    GLOAD2(ei, aI);
    GLOAD2(e0, a0); WLOAD(d0, (unsigned long long)(wordsp + t0 + 15 * tdir));
    GLOAD2(e1, a1); WLOAD(d1, (unsigned long long)(wordsp + t0 + 16 * tdir));
    GLOAD2(e2, a2); WLOAD(d2, (unsigned long long)(wordsp + t0 + 17 * tdir));
    GLOAD2(e3, a3); WLOAD(d3, (unsigned long long)(wordsp + t0 + 18 * tdir));
    GLOAD2(e4, a4); WLOAD(d4, (unsigned long long)(wordsp + t0 + 19 * tdir));
    GLOAD2(e5, a5); WLOAD(d5, (unsigned long long)(wordsp + t0 + 20 * tdir));
    GLOAD2(e6, a6); WLOAD(d6, (unsigned long long)(wordsp + t0 + 21 * tdir));
    GLOAD2(e7, a7); WLOAD(d7, (unsigned long long)(wordsp + t0 + 22 * tdir));
    GLOAD2(e8, a8); WLOAD(d8, (unsigned long long)(wordsp + t0 + 23 * tdir));
    GLOAD2(e9, a9); WLOAD(d9, (unsigned long long)(wordsp + t0 + 24 * tdir));
    GLOAD2(eA, aA); WLOAD(dA, (unsigned long long)(wordsp + t0 + 25 * tdir));
    GLOAD2(eB, aB); WLOAD(dB, (unsigned long long)(wordsp + t0 + 26 * tdir));
    GLOAD2(eC, aC); WLOAD(dC, (unsigned long long)(wordsp + t0 + 27 * tdir));
    GLOAD2(eD, aD); WLOAD(dD, (unsigned long long)(wordsp + t0 + 28 * tdir));

    SWAIT(42);                                   // ei (oldest 2) complete

    // X init = g o e_{t0}   (entry kc at ei[kc>>1], words (kc&1)*2, +1)
    bf16x4 X[4];
#pragma unroll
    for (int kc = 0; kc < 4; ++kc) {
        unsigned ex = ei[kc >> 1][(kc & 1) * 2];
        unsigned ey = ei[kc >> 1][(kc & 1) * 2 + 1];
        float f0 = __uint_as_float(ex << 16)         * g[kc][0];
        float f1 = __uint_as_float(ex & 0xffff0000u) * g[kc][1];
        float f2 = __uint_as_float(ey << 16)         * g[kc][2];
        float f3 = __uint_as_float(ey & 0xffff0000u) * g[kc][3];
        X[kc] = pack4(f0, f1, f2, f3);
    }

    float xf[4][4];                              // last step's f32 products

    // substep: MFMA (regs only); if batch head, ONE vmcnt(21) draining this
    // batch's 7 groups; consume emission, refill for s+14, word for s+28.
    auto substep = [&](u32x4 (&eb)[2], int& wd, int widx, bool batchwait) {
        f32x4 D[4];
#pragma unroll
        for (int mt = 0; mt < 4; ++mt) { f32x4 z = {0.f, 0.f, 0.f, 0.f}; D[mt] = z; }
#pragma unroll
        for (int kc = 0; kc < 4; ++kc)
#pragma unroll
            for (int mt = 0; mt < 4; ++mt)
                D[mt] = __builtin_amdgcn_mfma_f32_16x16x16bf16_1k(Sf[mt][kc], X[kc], D[mt], 0, 0, 0);
        if (batchwait) SWAIT(21);                // 7 oldest groups (3 ops ea.)
#pragma unroll
        for (int kc = 0; kc < 4; ++kc) {
            unsigned ex = eb[kc >> 1][(kc & 1) * 2];
            unsigned ey = eb[kc >> 1][(kc & 1) * 2 + 1];
            float f0 = __uint_as_float(ex << 16);
            float f1 = __uint_as_float(ex & 0xffff0000u);
            float f2 = __uint_as_float(ey << 16);
            float f3 = __uint_as_float(ey & 0xffff0000u);
            xf[kc][0] = D[kc][0] * f0;  xf[kc][1] = D[kc][1] * f1;
            xf[kc][2] = D[kc][2] * f2;  xf[kc][3] = D[kc][3] * f3;
            X[kc] = pack4(xf[kc][0], xf[kc][1], xf[kc][2], xf[kc][3]);
        }
        unsigned long long a = btbp + (unsigned long long)wd * 128u;
        GLOAD2(eb, a);
        WLOAD(wd, (unsigned long long)(wordsp + widx));
    };

    // 126 steps = 9 x 14 (two 7-batches per iter); word index bounds:
    // fwd max 1+(112+13+29)=155<256, bwd min 254-154=100>=0.
    for (int i = 0; i < 126; i += 14) {
        substep(e0, d0, t0 + tdir * (i + 29), true);
        substep(e1, d1, t0 + tdir * (i + 30), false);
        substep(e2, d2, t0 + tdir * (i + 31), false);
        substep(e3, d3, t0 + tdir * (i + 32), false);
        substep(e4, d4, t0 + tdir * (i + 33), false);
        substep(e5, d5, t0 + tdir * (i + 34), false);
        substep(e6, d6, t0 + tdir * (i + 35), false);
        substep(e7, d7, t0 + tdir * (i + 36), true);
        substep(e8, d8, t0 + tdir * (i + 37), false);
        substep(e9, d9, t0 + tdir * (i + 38), false);
        substep(eA, dA, t0 + tdir * (i + 39), false);
        substep(eB, dB, t0 + tdir * (i + 40), false);
        substep(eC, dC, t0 + tdir * (i + 41), false);
        substep(eD, dD, t0 + tdir * (i + 42), false);
    }

    if (wv == 0) {
        // extra step: Y = S^T alpha_127 (no emission) -> LDS
        f32x4 D[4];
#pragma unroll
        for (int mt = 0; mt < 4; ++mt) { f32x4 z = {0.f, 0.f, 0.f, 0.f}; D[mt] = z; }
#pragma unroll
        for (int kc = 0; kc < 4; ++kc)
#pragma unroll
            for (int mt = 0; mt < 4; ++mt)
                D[mt] = __builtin_amdgcn_mfma_f32_16x16x16bf16_1k(Sf[mt][kc], X[kc], D[mt], 0, 0, 0);
#pragma unroll
        for (int mt = 0; mt < 4; ++mt) {
            float4 o = {D[mt][0], D[mt][1], D[mt][2], D[mt][3]};
            *(float4*)&ytile[l * 68 + mt * 16 + q * 4] = o;
        }
    }
    __syncthreads();
    if (wv == 1) {
        // z[s] = sum_tag Y[tag][s] * X128[tag][s]
        float p = 0.f;
#pragma unroll
        for (int mt = 0; mt < 4; ++mt)
#pragma unroll
            for (int r = 0; r < 4; ++r)
                p = fmaf(ytile[l * 68 + mt * 16 + q * 4 + r], xf[mt][r], p);
        p += __shfl_xor(p, 16, 64);
        p += __shfl_xor(p, 32, 64);
        if (lane < 16)
            out[sbase + l] = logf(p) + 255.0f * LOG64;
    }
}

extern "C" void kernel_launch(void* const* d_in, const int* in_sizes, int n_in,
                              void* d_out, int out_size, void* d_ws, size_t ws_size,
                              hipStream_t stream) {
    const int*   words  = (const int*)d_in[0];
    const float* ThetaB = (const float*)d_in[1];
    const float* WA     = (const float*)d_in[2];
    const float* E      = (const float*)d_in[3];
    float*       outp   = (float*)d_out;
    uint2*       Btb    = (uint2*)d_ws;          // 50002*128 B = 6.4 MB

    // 782 blocks x 1 wave x 4 word-tiles = 50048 >= 50002 rows
    emis_mfma<<<dim3(782), dim3(64), 0, stream>>>(ThetaB, E, Btb);
    // 128 blocks x (fwd wave + bwd wave), 16 sentences each
    crf_fwdbwd<<<dim3(128), dim3(128), 0, stream>>>(words, WA, Btb, outp);
}

// Round 10
// 114.202 us; speedup vs baseline: 1.0755x; 1.0297x over previous
//
#include <hip/hip_runtime.h>

// CRF forward logZ. Inputs: words i32 [2048][256], ThetaB f32 [64][128],
// WA f32 [64][64], E f32 [50002][128]. out: f32 [2048].
// ws: Btb FP8-e4m3 [50002][64] = 3.2 MB, row layout [q][kc*4+j] (64 B/row).
//
// R15: emission table in FP8. Per-step VMEM instrs 3 -> 2: lane (q,l)'s 16
//      tags = 16 contiguous fp8 bytes = ONE global_load_dwordx4 (was 2x
//      dwordx4 over 32 B bf16). Surviving stall model: per-VMEM-instruction
//      address processing at the CU's TA/L1 (~64 lane-slots/instr, shared
//      by fwd+bwd waves) - invariant to ring depth/waits/occupancy (R11-R14
//      nulls), linear in instr count (R8->R9: 5->3 instrs = -188cy/step).
//      Values exp(theta.E) in [0.7,1.4] - ideal e4m3 range; encode+decode
//      via the chip's own cvt_pk_fp8 ops (self-consistent). Expected log-
//      error ~0.3 << threshold 21. Ring depth 14 + batched vmcnt kept
//      (R14); counts recomputed for 2-op groups. emis stores 1x dwordx4.

#define NROWS 50002
#define EOS_T 62
#define BOS_T 63
#define TLEN  256
#define LOG64 4.1588830833596715f

typedef __attribute__((ext_vector_type(4))) short bf16x4;
typedef __attribute__((ext_vector_type(8))) short bf16x8;
typedef __attribute__((ext_vector_type(2))) float f32x2;
typedef __attribute__((ext_vector_type(4))) float f32x4;
typedef __attribute__((ext_vector_type(4))) unsigned int u32x4;

// round-half-up f32->bf16 pair pack (2 add + 1 perm); lo in low 16 bits
static __device__ __forceinline__ unsigned pack_bf2(float lo, float hi) {
    unsigned a = __float_as_uint(lo) + 0x8000u;
    unsigned b = __float_as_uint(hi) + 0x8000u;
    return __builtin_amdgcn_perm(b, a, 0x07060302u);
}
static __device__ __forceinline__ bf16x8 pack8(float4 a, float4 b) {
    union { bf16x8 v; unsigned u[4]; } r;
    r.u[0] = pack_bf2(a.x, a.y); r.u[1] = pack_bf2(a.z, a.w);
    r.u[2] = pack_bf2(b.x, b.y); r.u[3] = pack_bf2(b.z, b.w);
    return r.v;
}
static __device__ __forceinline__ bf16x4 pack4(float f0, float f1, float f2, float f3) {
    union { bf16x4 v; unsigned u[2]; } r;
    r.u[0] = pack_bf2(f0, f1); r.u[1] = pack_bf2(f2, f3);
    return r.v;
}

// one Btb row slice for this lane: 16 contiguous bytes = 1x dwordx4 (crf).
#define GLOAD1(buf, addr)                                                     \
    asm volatile("global_load_dwordx4 %0, %1, off" : "=&v"(buf) : "v"(addr))
#define WLOAD(wd, addr)                                                       \
    asm volatile("global_load_dword %0, %1, off" : "=&v"(wd) : "v"(addr))
#define SWAIT(n)                                                              \
    do { __builtin_amdgcn_sched_barrier(0);                                   \
         asm volatile("s_waitcnt vmcnt(" #n ")");                             \
         __builtin_amdgcn_sched_barrier(0); } while (0)

// one E-row slice for this lane: 4x 32B spans (kc*128 + q-slice), 8x dwordx4.
#define GLOADE(buf, addr)                                                     \
    asm volatile("global_load_dwordx4 %0, %8, off\n\t"                        \
                 "global_load_dwordx4 %1, %8, off offset:16\n\t"              \
                 "global_load_dwordx4 %2, %8, off offset:128\n\t"             \
                 "global_load_dwordx4 %3, %8, off offset:144\n\t"             \
                 "global_load_dwordx4 %4, %8, off offset:256\n\t"             \
                 "global_load_dwordx4 %5, %8, off offset:272\n\t"             \
                 "global_load_dwordx4 %6, %8, off offset:384\n\t"             \
                 "global_load_dwordx4 %7, %8, off offset:400"                 \
                 : "=&v"(buf[0]), "=&v"(buf[1]), "=&v"(buf[2]), "=&v"(buf[3]),\
                   "=&v"(buf[4]), "=&v"(buf[5]), "=&v"(buf[6]), "=&v"(buf[7]) \
                 : "v"(addr))
#define GSTORE1(addr, o)                                                      \
    asm volatile("global_store_dwordx4 %0, %1, off"                           \
                 :: "v"(addr), "v"(o) : "memory")

// ---------------------------------------------------------------------------
// Kernel 1: Btb fp8 row w: byte q*16 + mt*4 + r = e4m3(exp(ThetaB[tag].E[w])),
// tag = mt*16 + q*4 + r; tags 62,63 -> 0. MFMA GEMM as before; each lane
// packs its (q, mt) dword via v_cvt_pk_fp8_f32 and stores 16 B contiguous.
// ---------------------------------------------------------------------------
__global__ __launch_bounds__(64, 1) void emis_mfma(
    const float* __restrict__ ThetaB, const float* __restrict__ E,
    unsigned* __restrict__ Btb)
{
    const int l = threadIdx.x & 15;
    const int q = threadIdx.x >> 4;

    bf16x8 Af[4][4];
#pragma unroll
    for (int mt = 0; mt < 4; ++mt)
#pragma unroll
        for (int kc = 0; kc < 4; ++kc) {
            const float4* tp = (const float4*)ThetaB + (mt * 16 + l) * 32 + kc * 8 + q * 2;
            Af[mt][kc] = pack8(tp[0], tp[1]);
        }

    const int base0 = blockIdx.x * 64;
    unsigned long long ea[4], sa[4];
#pragma unroll
    for (int it = 0; it < 4; ++it) {
        int row  = base0 + it * 16 + l;
        int rowc = row < NROWS ? row : NROWS - 1;       // clamped rows write
        ea[it] = (unsigned long long)(const char*)E + (unsigned long long)rowc * 512u + (unsigned)(q * 32);
        sa[it] = (unsigned long long)(char*)Btb     + (unsigned long long)rowc * 64u  + (unsigned)(q * 16);
    }

    asm volatile("s_waitcnt vmcnt(0) lgkmcnt(0)");
    __builtin_amdgcn_sched_barrier(0);

    u32x4 b0[8], b1[8], b2[8];
    GLOADE(b0, ea[0]); GLOADE(b1, ea[1]); GLOADE(b2, ea[2]);   // 24 in flight

    auto ctile = [&](u32x4 (&buf)[8], unsigned long long saddr, int refill,
                     unsigned long long raddr) {
        bf16x8 Bf[4];
#pragma unroll
        for (int kc = 0; kc < 4; ++kc)
            Bf[kc] = pack8(*(const float4*)&buf[kc * 2], *(const float4*)&buf[kc * 2 + 1]);
        if (refill) GLOADE(buf, raddr);
        f32x4 D[4];
#pragma unroll
        for (int mt = 0; mt < 4; ++mt) { f32x4 z = {0.f, 0.f, 0.f, 0.f}; D[mt] = z; }
#pragma unroll
        for (int kc = 0; kc < 4; ++kc)
#pragma unroll
            for (int mt = 0; mt < 4; ++mt)
                D[mt] = __builtin_amdgcn_mfma_f32_16x16x32_bf16(Af[mt][kc], Bf[kc], D[mt], 0, 0, 0);
        u32x4 o;
#pragma unroll
        for (int mt = 0; mt < 4; ++mt) {
            float v0 = expf(D[mt][0]), v1 = expf(D[mt][1]);
            float v2 = expf(D[mt][2]), v3 = expf(D[mt][3]);
            if (mt == 3 && q == 3) { v2 = 0.f; v3 = 0.f; }     // tags 62, 63
            int d = __builtin_amdgcn_cvt_pk_fp8_f32(v0, v1, 0, false);
            d     = __builtin_amdgcn_cvt_pk_fp8_f32(v2, v3, d, true);
            o[mt] = (unsigned)d;
        }
        GSTORE1(saddr, o);
    };

    SWAIT(16);                       // T0 ready (L1,L2 remain)
    ctile(b0, sa[0], 1, ea[3]);      // + refill L3, store S0 -> 25 out
    SWAIT(17);                       // retire L1; L2+L3+S0 = 17
    ctile(b1, sa[1], 0, 0);          // store S1 -> 18
    SWAIT(10);                       // retire L2; L3+S0+S1 = 10
    ctile(b2, sa[2], 0, 0);          // store S2 -> 11
    SWAIT(3);                        // retire L3; S0+S1+S2 = 3
    ctile(b0, sa[3], 0, 0);          // T3, store S3
}

// ---------------------------------------------------------------------------
// Kernel 2: fwd/bwd recurrence, fully in registers. Ring depth 14, groups of
// 2 VMEM (1 fp8 gather dwordx4 + 1 word); waits batched: one vmcnt(14) per
// 7 substeps drains 7 groups. fp8 decode via v_cvt_pk_f32_fp8 (2 per kc).
// fwd (wv=0): A = S^T, X' = (S^T X) o e_t; bwd (wv=1): X' = e_t o (S X).
// Join: z = (S^T alpha_127) . (e_128 o q_129) via one LDS tile + dot.
// ---------------------------------------------------------------------------
__global__ __launch_bounds__(128, 1) void crf_fwdbwd(
    const int* __restrict__ words, const float* __restrict__ WA,
    const unsigned* __restrict__ Btb, float* __restrict__ out)
{
    __shared__ float ytile[16 * 68];
    const int lane  = threadIdx.x & 63;
    const int wv    = threadIdx.x >> 6;          // 0 = fwd, 1 = bwd
    const int l     = lane & 15;
    const int q     = lane >> 4;
    const int sbase = blockIdx.x * 16;

    // Transition A-frags. S[i][j] = exp(WA[i][j]) * (j != BOS)/64.
    bf16x4 Sf[4][4];
#pragma unroll
    for (int mt = 0; mt < 4; ++mt)
#pragma unroll
        for (int kc = 0; kc < 4; ++kc) {
            float t[4];
#pragma unroll
            for (int j = 0; j < 4; ++j) {
                const int mg = mt * 16 + l;          // m index
                const int kg = kc * 16 + q * 4 + j;  // k index
                const int ii = wv ? mg : kg;         // WA row
                const int jj = wv ? kg : mg;         // WA col (masked: S's j)
                t[j] = (jj == BOS_T) ? 0.f : expf(WA[ii * 64 + jj]) * 0.015625f;
            }
            Sf[mt][kc] = pack4(t[0], t[1], t[2], t[3]);
        }

    float g[4][4];
#pragma unroll
    for (int kc = 0; kc < 4; ++kc)
#pragma unroll
        for (int e = 0; e < 4; ++e) {
            const int jt = kc * 16 + q * 4 + e;
            g[kc][e] = wv ? expf(WA[jt * 64 + EOS_T]) * 0.015625f
                          : ((jt == BOS_T) ? 0.f : expf(WA[BOS_T * 64 + jt]) * 0.015625f);
        }

    const int wb   = (sbase + l) * TLEN;
    const int tdir = wv ? -1 : 1;
    const int t0   = wv ? 254 : 1;

    // lane's 16B fp8 slice of a Btb row starts at byte q*16
    const unsigned long long btbp   = (unsigned long long)(const char*)Btb + (unsigned)(q * 16);
    const int*               wordsp = words + wb;

    // -------- prologue: 15 words via normal loads, then asm-issue region ----
    const int w0  = wordsp[t0];
    const int w1  = wordsp[t0 + 1  * tdir], w2  = wordsp[t0 + 2  * tdir];
    const int w3  = wordsp[t0 + 3  * tdir], w4  = wordsp[t0 + 4  * tdir];
    const int w5  = wordsp[t0 + 5  * tdir], w6  = wordsp[t0 + 6  * tdir];
    const int w7  = wordsp[t0 + 7  * tdir], w8  = wordsp[t0 + 8  * tdir];
    const int w9  = wordsp[t0 + 9  * tdir], w10 = wordsp[t0 + 10 * tdir];
    const int w11 = wordsp[t0 + 11 * tdir], w12 = wordsp[t0 + 12 * tdir];
    const int w13 = wordsp[t0 + 13 * tdir], w14 = wordsp[t0 + 14 * tdir];

    unsigned long long aI = btbp + (unsigned long long)w0  * 64u;
    unsigned long long a0 = btbp + (unsigned long long)w1  * 64u;
    unsigned long long a1 = btbp + (unsigned long long)w2  * 64u;
    unsigned long long a2 = btbp + (unsigned long long)w3  * 64u;
    unsigned long long a3 = btbp + (unsigned long long)w4  * 64u;
    unsigned long long a4 = btbp + (unsigned long long)w5  * 64u;
    unsigned long long a5 = btbp + (unsigned long long)w6  * 64u;
    unsigned long long a6 = btbp + (unsigned long long)w7  * 64u;
    unsigned long long a7 = btbp + (unsigned long long)w8  * 64u;
    unsigned long long a8 = btbp + (unsigned long long)w9  * 64u;
    unsigned long long a9 = btbp + (unsigned long long)w10 * 64u;
    unsigned long long aA = btbp + (unsigned long long)w11 * 64u;
    unsigned long long aB = btbp + (unsigned long long)w12 * 64u;
    unsigned long long aC = btbp + (unsigned long long)w13 * 64u;
    unsigned long long aD = btbp + (unsigned long long)w14 * 64u;

    // drain ALL compiler-issued vmem so manual vmcnt counts are exact
    asm volatile("s_waitcnt vmcnt(0) lgkmcnt(0)");
    __builtin_amdgcn_sched_barrier(0);

    u32x4 ei, e0, e1, e2, e3, e4, e5, e6, e7, e8, e9, eA, eB, eC, eD;
    int d0, d1, d2, d3, d4, d5, d6, d7, d8, d9, dA, dB, dC, dD;
    // issue groups: [ei:1], then 14x [1 gather + 1 word] = 29 ops
    GLOAD1(ei, aI);
    GLOAD1(e0, a0); WLOAD(d0, (unsigned long long)(wordsp + t0 + 15 * tdir));
    GLOAD1(e1, a1); WLOAD(d1, (unsigned long long)(wordsp + t0 + 16 * tdir));
    GLOAD1(e2, a2); WLOAD(d2, (unsigned long long)(wordsp + t0 + 17 * tdir));
    GLOAD1(e3, a3); WLOAD(d3, (unsigned long long)(wordsp + t0 + 18 * tdir));
    GLOAD1(e4, a4); WLOAD(d4, (unsigned long long)(wordsp + t0 + 19 * tdir));
    GLOAD1(e5, a5); WLOAD(d5, (unsigned long long)(wordsp + t0 + 20 * tdir));
    GLOAD1(e6, a6); WLOAD(d6, (unsigned long long)(wordsp + t0 + 21 * tdir));
    GLOAD1(e7, a7); WLOAD(d7, (unsigned long long)(wordsp + t0 + 22 * tdir));
    GLOAD1(e8, a8); WLOAD(d8, (unsigned long long)(wordsp + t0 + 23 * tdir));
    GLOAD1(e9, a9); WLOAD(d9, (unsigned long long)(wordsp + t0 + 24 * tdir));
    GLOAD1(eA, aA); WLOAD(dA, (unsigned long long)(wordsp + t0 + 25 * tdir));
    GLOAD1(eB, aB); WLOAD(dB, (unsigned long long)(wordsp + t0 + 26 * tdir));
    GLOAD1(eC, aC); WLOAD(dC, (unsigned long long)(wordsp + t0 + 27 * tdir));
    GLOAD1(eD, aD); WLOAD(dD, (unsigned long long)(wordsp + t0 + 28 * tdir));

    SWAIT(28);                                   // ei (oldest 1) complete

    // X init = g o e_{t0}; dword kc = 4 fp8 = tags kc*16+q*4+{0..3}
    bf16x4 X[4];
#pragma unroll
    for (int kc = 0; kc < 4; ++kc) {
        f32x2 p01 = __builtin_amdgcn_cvt_pk_f32_fp8((int)ei[kc], false);
        f32x2 p23 = __builtin_amdgcn_cvt_pk_f32_fp8((int)ei[kc], true);
        X[kc] = pack4(p01[0] * g[kc][0], p01[1] * g[kc][1],
                      p23[0] * g[kc][2], p23[1] * g[kc][3]);
    }

    float xf[4][4];                              // last step's f32 products

    // substep: MFMA (regs only); if batch head, ONE vmcnt(14) draining this
    // batch's 7 groups; fp8-decode emission, refill for s+14, word for s+28.
    auto substep = [&](u32x4& eb, int& wd, int widx, bool batchwait) {
        f32x4 D[4];
#pragma unroll
        for (int mt = 0; mt < 4; ++mt) { f32x4 z = {0.f, 0.f, 0.f, 0.f}; D[mt] = z; }
#pragma unroll
        for (int kc = 0; kc < 4; ++kc)
#pragma unroll
            for (int mt = 0; mt < 4; ++mt)
                D[mt] = __builtin_amdgcn_mfma_f32_16x16x16bf16_1k(Sf[mt][kc], X[kc], D[mt], 0, 0, 0);
        if (batchwait) SWAIT(14);                // 7 oldest groups (2 ops ea.)
#pragma unroll
        for (int kc = 0; kc < 4; ++kc) {
            f32x2 p01 = __builtin_amdgcn_cvt_pk_f32_fp8((int)eb[kc], false);
            f32x2 p23 = __builtin_amdgcn_cvt_pk_f32_fp8((int)eb[kc], true);
            xf[kc][0] = D[kc][0] * p01[0];  xf[kc][1] = D[kc][1] * p01[1];
            xf[kc][2] = D[kc][2] * p23[0];  xf[kc][3] = D[kc][3] * p23[1];
            X[kc] = pack4(xf[kc][0], xf[kc][1], xf[kc][2], xf[kc][3]);
        }
        unsigned long long a = btbp + (unsigned long long)wd * 64u;
        GLOAD1(eb, a);
        WLOAD(wd, (unsigned long long)(wordsp + widx));
    };

    // 126 steps = 9 x 14 (two 7-batches per iter); word index bounds:
    // fwd max 1+(112+42)=155<256, bwd min 254-154=100>=0.
    for (int i = 0; i < 126; i += 14) {
        substep(e0, d0, t0 + tdir * (i + 29), true);
        substep(e1, d1, t0 + tdir * (i + 30), false);
        substep(e2, d2, t0 + tdir * (i + 31), false);
        substep(e3, d3, t0 + tdir * (i + 32), false);
        substep(e4, d4, t0 + tdir * (i + 33), false);
        substep(e5, d5, t0 + tdir * (i + 34), false);
        substep(e6, d6, t0 + tdir * (i + 35), false);
        substep(e7, d7, t0 + tdir * (i + 36), true);
        substep(e8, d8, t0 + tdir * (i + 37), false);
        substep(e9, d9, t0 + tdir * (i + 38), false);
        substep(eA, dA, t0 + tdir * (i + 39), false);
        substep(eB, dB, t0 + tdir * (i + 40), false);
        substep(eC, dC, t0 + tdir * (i + 41), false);
        substep(eD, dD, t0 + tdir * (i + 42), false);
    }

    if (wv == 0) {
        // extra step: Y = S^T alpha_127 (no emission) -> LDS
        f32x4 D[4];
#pragma unroll
        for (int mt = 0; mt < 4; ++mt) { f32x4 z = {0.f, 0.f, 0.f, 0.f}; D[mt] = z; }
#pragma unroll
        for (int kc = 0; kc < 4; ++kc)
#pragma unroll
            for (int mt = 0; mt < 4; ++mt)
                D[mt] = __builtin_amdgcn_mfma_f32_16x16x16bf16_1k(Sf[mt][kc], X[kc], D[mt], 0, 0, 0);
#pragma unroll
        for (int mt = 0; mt < 4; ++mt) {
            float4 o = {D[mt][0], D[mt][1], D[mt][2], D[mt][3]};
            *(float4*)&ytile[l * 68 + mt * 16 + q * 4] = o;
        }
    }
    __syncthreads();
    if (wv == 1) {
        // z[s] = sum_tag Y[tag][s] * X128[tag][s]
        float p = 0.f;
#pragma unroll
        for (int mt = 0; mt < 4; ++mt)
#pragma unroll
            for (int r = 0; r < 4; ++r)
                p = fmaf(ytile[l * 68 + mt * 16 + q * 4 + r], xf[mt][r], p);
        p += __shfl_xor(p, 16, 64);
        p += __shfl_xor(p, 32, 64);
        if (lane < 16)
            out[sbase + l] = logf(p) + 255.0f * LOG64;
    }
}

extern "C" void kernel_launch(void* const* d_in, const int* in_sizes, int n_in,
                              void* d_out, int out_size, void* d_ws, size_t ws_size,
                              hipStream_t stream) {
    const int*   words  = (const int*)d_in[0];
    const float* ThetaB = (const float*)d_in[1];
    const float* WA     = (const float*)d_in[2];
    const float* E      = (const float*)d_in[3];
    float*       outp   = (float*)d_out;
    unsigned*    Btb    = (unsigned*)d_ws;       // 50002*64 B = 3.2 MB fp8

    // 782 blocks x 1 wave x 4 word-tiles = 50048 >= 50002 rows
    emis_mfma<<<dim3(782), dim3(64), 0, stream>>>(ThetaB, E, Btb);
    // 128 blocks x (fwd wave + bwd wave), 16 sentences each
    crf_fwdbwd<<<dim3(128), dim3(128), 0, stream>>>(words, WA, Btb, outp);
}